// Round 13
// baseline (359.774 us; speedup 1.0000x reference)
//
#include <hip/hip_runtime.h>

using half8 = __attribute__((ext_vector_type(8))) _Float16;
using f32x4 = __attribute__((ext_vector_type(4))) float;

typedef __attribute__((address_space(3))) unsigned int lds_uint;
typedef __attribute__((address_space(1))) const unsigned int glb_uint;
__device__ __forceinline__ void async_copy16(const void* g, void* l) {
  __builtin_amdgcn_global_load_lds((glb_uint*)g, (lds_uint*)l, 16, 0, 0);
}

// raw barrier WITHOUT the implicit vmcnt(0) drain of __syncthreads()
__device__ __forceinline__ void raw_barrier() {
  asm volatile("" ::: "memory");
  __builtin_amdgcn_s_barrier();
  asm volatile("" ::: "memory");
}

// ---------------- prep weights (fp16) + zero cnt/cur, one dispatch ----------------
__global__ void prep_zero_kernel(const float* __restrict__ W1l, const float* __restrict__ W1r,
                                 const float* __restrict__ W2l, const float* __restrict__ W2r,
                                 const float* __restrict__ W3l, const float* __restrict__ W3r,
                                 const float* __restrict__ W4l, const float* __restrict__ W4r,
                                 _Float16* __restrict__ w1, _Float16* __restrict__ w2,
                                 _Float16* __restrict__ w3, _Float16* __restrict__ w4,
                                 int4* __restrict__ zp, int n4) {
  int i = blockIdx.x * 256 + threadIdx.x;
  if (i < 98304) {  // w1: 128*768
    int c = i / 768, k = i - c * 768;
    float v = (c < 64) ? W1l[k * 64 + c] : W1r[k * 64 + (c - 64)];
    w1[i] = (_Float16)v;
  } else if (i < 98304 + 4096) {  // w2: [64][64]
    int j = i - 98304;
    int c = j >> 6, k = j & 63;
    float v = (c < 32) ? W2l[k * 32 + c] : W2r[k * 32 + (c - 32)];
    w2[j] = (_Float16)v;
  } else if (i < 98304 + 4096 + 1024) {  // w3: [32][32]
    int j = i - (98304 + 4096);
    int c = j >> 5, k = j & 31;
    float v = (c < 16) ? W3l[k * 16 + c] : W3r[k * 16 + (c - 16)];
    w3[j] = (_Float16)v;
  } else if (i < 98304 + 4096 + 1024 + 512) {  // w4: [16][32]
    int j = i - (98304 + 4096 + 1024);
    int c = j >> 5, k = j & 31;
    float v = 0.f;
    if (k < 16) {
      if (c < 5) v = W4l[k * 5 + c];
      else if (c < 10) v = W4r[k * 5 + (c - 5)];
    }
    w4[j] = (_Float16)v;
  } else {
    int j = i - (98304 + 4096 + 1024 + 512);
    if (j < n4) zp[j] = make_int4(0, 0, 0, 0);
  }
}

// ---------------- CSR build ----------------
__global__ void deg_kernel(const int* __restrict__ dst, int* __restrict__ cnt, int e) {
  int i = blockIdx.x * 256 + threadIdx.x;
  if (i < e) atomicAdd(&cnt[dst[i]], 1);
}

__global__ void scan1_kernel(const int* __restrict__ cnt, int* __restrict__ off,
                             int* __restrict__ bsum, float* __restrict__ invd, int nodes) {
  __shared__ int sh[256];
  int tid = threadIdx.x;
  int base = blockIdx.x * 1024 + tid * 4;
  int a0 = (base + 0 < nodes) ? cnt[base + 0] : 0;
  int a1 = (base + 1 < nodes) ? cnt[base + 1] : 0;
  int a2 = (base + 2 < nodes) ? cnt[base + 2] : 0;
  int a3 = (base + 3 < nodes) ? cnt[base + 3] : 0;
  if (base + 0 < nodes) invd[base + 0] = a0 > 0 ? 1.0f / (float)a0 : 0.f;
  if (base + 1 < nodes) invd[base + 1] = a1 > 0 ? 1.0f / (float)a1 : 0.f;
  if (base + 2 < nodes) invd[base + 2] = a2 > 0 ? 1.0f / (float)a2 : 0.f;
  if (base + 3 < nodes) invd[base + 3] = a3 > 0 ? 1.0f / (float)a3 : 0.f;
  int s3 = a0 + a1 + a2 + a3;
  sh[tid] = s3;
  __syncthreads();
  for (int d = 1; d < 256; d <<= 1) {
    int v = (tid >= d) ? sh[tid - d] : 0;
    __syncthreads();
    sh[tid] += v;
    __syncthreads();
  }
  int excl = sh[tid] - s3;
  if (base + 0 <= nodes) off[base + 0] = excl;
  if (base + 1 <= nodes) off[base + 1] = excl + a0;
  if (base + 2 <= nodes) off[base + 2] = excl + a0 + a1;
  if (base + 3 <= nodes) off[base + 3] = excl + a0 + a1 + a2;
  if (tid == 255) bsum[blockIdx.x] = sh[255];
}

__global__ void scan2_kernel(int* __restrict__ bsum, int nb) {
  __shared__ int sh[128];
  int tid = threadIdx.x;
  int v = (tid < nb) ? bsum[tid] : 0;
  sh[tid] = v;
  __syncthreads();
  for (int d = 1; d < 128; d <<= 1) {
    int u = (tid >= d) ? sh[tid - d] : 0;
    __syncthreads();
    sh[tid] += u;
    __syncthreads();
  }
  if (tid < nb) bsum[tid] = sh[tid] - v;
}

__global__ void scan3_kernel(int* __restrict__ off, const int* __restrict__ bsum, int ntot) {
  int i = blockIdx.x * 256 + threadIdx.x;
  if (i < ntot) off[i] += bsum[i >> 10];
}

// ---------------- MEGA: layer-1 GEMM blocks + sortfill blocks, one dispatch ----------
// gemm and sortfill are mutually independent; sortfill's ~15us serial slot hides under
// the gemm's ~120us. gemm path = R8/R11 config (best measured): 128-row tile, BK=32,
// 48KB LDS dbuf, counted vmcnt(6), raw barriers.
__global__ __launch_bounds__(256, 3) void gemm1_sortfill_kernel(
    const float* __restrict__ x, const _Float16* __restrict__ w16,
    const float* __restrict__ bias, _Float16* __restrict__ p, _Float16* __restrict__ q,
    int n, int gemm_gb, const int* __restrict__ esrc, const int* __restrict__ edst,
    const int* __restrict__ off, int* __restrict__ cur, int* __restrict__ csr, int E) {
  if ((int)blockIdx.x >= gemm_gb) {
    // ---- sortfill path ----
    int i = ((int)blockIdx.x - gemm_gb) * 256 + threadIdx.x;
    if (i < E) {
      int d = edst[i];
      int pos = atomicAdd(&cur[d], 1);
      csr[off[d] + pos] = esrc[i];
    }
    return;
  }
  // ---- gemm path ----
  constexpr int DI = 768, BK = 32, NT = DI / BK;
  __shared__ float aS[2][128 * BK];     // 2 x 16 KB
  __shared__ _Float16 bS[2][128 * BK];  // 2 x 8 KB
  int t = threadIdx.x;
  int lane = t & 63, w = t >> 6;
  int lm = lane & 15, lk = lane >> 4;
  int m0 = blockIdx.x * 128;

  const float* agp[4];
  int abase[4];
#pragma unroll
  for (int j = 0; j < 4; ++j) {
    int g = (j * 4 + w) * 64 + lane;
    int row = g >> 3, gi = g & 7;
    int gj = gi ^ (row & 7);
    int grow = m0 + row;
    if (grow >= n) grow = n - 1;
    agp[j] = x + (size_t)grow * DI + gj * 4;
    abase[j] = (j * 4 + w) * 256;
  }
  const _Float16* bgp[2];
  int bbase[2];
#pragma unroll
  for (int j = 0; j < 2; ++j) {
    int g = (j * 4 + w) * 64 + lane;
    int c = g >> 2, gi = g & 3;
    int gj = gi ^ ((c >> 1) & 3);
    bgp[j] = w16 + (size_t)c * DI + gj * 8;
    bbase[j] = (j * 4 + w) * 512;
  }

  f32x4 acc[2][8];
#pragma unroll
  for (int mi = 0; mi < 2; ++mi)
#pragma unroll
    for (int ni = 0; ni < 8; ++ni) acc[mi][ni] = (f32x4){0.f, 0.f, 0.f, 0.f};

  int r0l = w * 32 + lm, r1l = r0l + 16;
  int sw = lm & 7;
  int bsw = (lk ^ ((lm >> 1) & 3)) << 3;

  auto compute_tile = [&](const float* ab, const _Float16* bb) {
    f32x4 v0a = *(const f32x4*)(ab + r0l * 32 + (((lk * 2 + 0) ^ sw) << 2));
    f32x4 v0b = *(const f32x4*)(ab + r0l * 32 + (((lk * 2 + 1) ^ sw) << 2));
    f32x4 v1a = *(const f32x4*)(ab + r1l * 32 + (((lk * 2 + 0) ^ sw) << 2));
    f32x4 v1b = *(const f32x4*)(ab + r1l * 32 + (((lk * 2 + 1) ^ sw) << 2));
    half8 a0, a1;
#pragma unroll
    for (int j = 0; j < 4; ++j) {
      a0[j] = (_Float16)v0a[j]; a0[4 + j] = (_Float16)v0b[j];
      a1[j] = (_Float16)v1a[j]; a1[4 + j] = (_Float16)v1b[j];
    }
#pragma unroll
    for (int ni = 0; ni < 8; ++ni) {
      half8 b = *(const half8*)(bb + ni * 512 + lm * 32 + bsw);
      acc[0][ni] = __builtin_amdgcn_mfma_f32_16x16x32_f16(a0, b, acc[0][ni], 0, 0, 0);
      acc[1][ni] = __builtin_amdgcn_mfma_f32_16x16x32_f16(a1, b, acc[1][ni], 0, 0, 0);
    }
  };

#pragma unroll
  for (int j = 0; j < 4; ++j) async_copy16(agp[j], &aS[0][abase[j]]);
#pragma unroll
  for (int j = 0; j < 2; ++j) async_copy16(bgp[j], &bS[0][bbase[j]]);

  for (int ts = 0; ts < NT - 1; ++ts) {
    int cur2 = ts & 1;
    int kc = (ts + 1) * BK;
#pragma unroll
    for (int j = 0; j < 4; ++j) async_copy16(agp[j] + kc, &aS[cur2 ^ 1][abase[j]]);
#pragma unroll
    for (int j = 0; j < 2; ++j) async_copy16(bgp[j] + kc, &bS[cur2 ^ 1][bbase[j]]);
    asm volatile("s_waitcnt vmcnt(6)" ::: "memory");
    raw_barrier();
    compute_tile(aS[cur2], bS[cur2]);
    raw_barrier();
  }
  asm volatile("s_waitcnt vmcnt(0)" ::: "memory");
  raw_barrier();
  compute_tile(aS[(NT - 1) & 1], bS[(NT - 1) & 1]);

#pragma unroll
  for (int mi = 0; mi < 2; ++mi)
#pragma unroll
    for (int ni = 0; ni < 8; ++ni) {
      int col = ni * 16 + lm;
#pragma unroll
      for (int j = 0; j < 4; ++j) {
        int row = m0 + w * 32 + mi * 16 + lk * 4 + j;
        if (row < n) {
          float v = acc[mi][ni][j];
          if (col < 64) p[(size_t)row * 64 + col] = (_Float16)v;
          else q[(size_t)row * 64 + (col - 64)] = (_Float16)(v + bias[col - 64]);
        }
      }
    }
}

// ---------------- fused aggregate(+relu) -> gemm, edge-parallel Phase A ----------------
// Phase A: per node, C8 chunks x (64/C8) edges gathered SIMULTANEOUSLY by one wave
// (full 128B row per edge, coalesced), fp32 accum, log2(64/C8)-step shfl_xor butterfly
// over e_sub. deg~8 -> ~1 memory round-trip/node (was 4-8 serial), no cross-node
// divergence. Phase B: 8 waves x 16 rows MFMA from LDS.
template <int DIR, int DIP, int PSI, int NC, int NCR, int DO, int PSO>
__global__ __launch_bounds__(512) void fused_agg_gemm_kernel(
    const _Float16* __restrict__ pin, const _Float16* __restrict__ qin,
    const int* __restrict__ off, const int* __restrict__ csr, const float* __restrict__ invd,
    const _Float16* __restrict__ w16, const float* __restrict__ bias,
    _Float16* __restrict__ pout, _Float16* __restrict__ qout, int n) {
  constexpr int SP = DIP + 8;
  constexpr int C8 = DIR / 8;  // half8 chunks per node: 8/4/2
  constexpr int LOG2C8 = (C8 == 8) ? 3 : ((C8 == 4) ? 2 : 1);
  constexpr int EPAR = 64 / C8;  // edges in parallel per wave
  constexpr int NF = NC / 16;
  __shared__ _Float16 hs[128 * SP];
  int t = threadIdx.x;
  int lane = t & 63, w = t >> 6;
  int chunk = lane & (C8 - 1);
  int e_sub = lane >> LOG2C8;
  const half8* p8 = (const half8*)pin;

  for (int i = w; i < 128; i += 8) {  // wave w handles nodes i = w, w+8, ...
    int node = blockIdx.x * 128 + i;
    if (node < n) {
      int e0 = off[node], e1 = off[node + 1];
      float s[8];
#pragma unroll
      for (int j = 0; j < 8; ++j) s[j] = 0.f;
      for (int eb = e0; eb < e1; eb += EPAR) {
        int e = eb + e_sub;
        if (e < e1) {
          int src = csr[e];
          half8 v = p8[(size_t)src * PSI + chunk];
#pragma unroll
          for (int j = 0; j < 8; ++j) s[j] += (float)v[j];
        }
      }
#pragma unroll
      for (int m = C8; m < 64; m <<= 1)
#pragma unroll
        for (int j = 0; j < 8; ++j) s[j] += __shfl_xor(s[j], m);
      if (e_sub == 0) {
        float id = invd[node];
        half8 qv = ((const half8*)qin)[(size_t)node * PSI + chunk];
        half8 o;
#pragma unroll
        for (int j = 0; j < 8; ++j) o[j] = (_Float16)fmaxf(s[j] * id + (float)qv[j], 0.f);
        *(half8*)(hs + i * SP + chunk * 8) = o;
        if (DIP > DIR) {  // zero-pad k (layer 4)
          half8 z = {};
          *(half8*)(hs + i * SP + (chunk + C8) * 8) = z;
        }
      }
    }
  }
  __syncthreads();

  // Phase B: 8 waves x 16 rows
  int lm = lane & 15, lk = lane >> 4;
  int row_l = w * 16 + lm;
  const _Float16* wp = w16 + (size_t)lm * DIP + lk * 8;
  f32x4 acc[NF];
#pragma unroll
  for (int ni = 0; ni < NF; ++ni) acc[ni] = (f32x4){0.f, 0.f, 0.f, 0.f};
#pragma unroll
  for (int kc = 0; kc < DIP; kc += 32) {
    half8 a = *(const half8*)(hs + row_l * SP + kc + lk * 8);
#pragma unroll
    for (int ni = 0; ni < NF; ++ni) {
      half8 b = *(const half8*)(wp + (size_t)ni * 16 * DIP + kc);
      acc[ni] = __builtin_amdgcn_mfma_f32_16x16x32_f16(a, b, acc[ni], 0, 0, 0);
    }
  }
#pragma unroll
  for (int ni = 0; ni < NF; ++ni) {
    int col = ni * 16 + lm;
    if (col >= NCR) continue;
#pragma unroll
    for (int j = 0; j < 4; ++j) {
      int row = blockIdx.x * 128 + w * 16 + lk * 4 + j;
      if (row < n) {
        float v = acc[ni][j];
        if (col < DO) pout[(size_t)row * PSO + col] = (_Float16)v;
        else qout[(size_t)row * PSO + (col - DO)] = (_Float16)(v + bias[col - DO]);
      }
    }
  }
}

// final aggregation: 8 lanes/node edge-parallel, 3-step butterfly. out fp32 [n][5].
__global__ __launch_bounds__(256) void aggregate_last_kernel(
    const _Float16* __restrict__ p, const _Float16* __restrict__ q,
    const int* __restrict__ off, const int* __restrict__ csr,
    const float* __restrict__ invd, float* __restrict__ out, int n) {
  int t = threadIdx.x;
  int lane = t & 63, w = t >> 6;
  int node_sub = lane >> 3, e_sub = lane & 7;
  int node = blockIdx.x * 32 + w * 8 + node_sub;
  if (node >= n) return;
  int e0 = off[node], e1 = off[node + 1];
  const half8* p8 = (const half8*)p;
  float s[8];
#pragma unroll
  for (int j = 0; j < 8; ++j) s[j] = 0.f;
  for (int eb = e0; eb < e1; eb += 8) {
    int e = eb + e_sub;
    if (e < e1) {
      half8 v = p8[csr[e]];
#pragma unroll
      for (int j = 0; j < 8; ++j) s[j] += (float)v[j];
    }
  }
#pragma unroll
  for (int m = 1; m <= 4; m <<= 1)
#pragma unroll
    for (int j = 0; j < 8; ++j) s[j] += __shfl_xor(s[j], m);
  if (e_sub == 0) {
    float id = invd[node];
    half8 qv = ((const half8*)q)[node];
#pragma unroll
    for (int j = 0; j < 5; ++j) out[(size_t)node * 5 + j] = s[j] * id + (float)qv[j];
  }
}

// ---------------- launch ----------------
extern "C" void kernel_launch(void* const* d_in, const int* in_sizes, int n_in,
                              void* d_out, int out_size, void* d_ws, size_t ws_size,
                              hipStream_t stream) {
  const float* x = (const float*)d_in[0];
  const int* ei = (const int*)d_in[1];
  const int E = in_sizes[1] / 2;
  const int* esrc = ei;
  const int* edst = ei + E;
  const float* W1l = (const float*)d_in[3];
  const float* W1r = (const float*)d_in[4];
  const float* b1 = (const float*)d_in[5];
  const float* W2l = (const float*)d_in[6];
  const float* W2r = (const float*)d_in[7];
  const float* b2 = (const float*)d_in[8];
  const float* W3l = (const float*)d_in[9];
  const float* W3r = (const float*)d_in[10];
  const float* b3 = (const float*)d_in[11];
  const float* W4l = (const float*)d_in[12];
  const float* W4r = (const float*)d_in[13];
  const float* b4 = (const float*)d_in[14];
  const int N = in_sizes[0] / 768;
  float* out = (float*)d_out;
  (void)n_in; (void)out_size; (void)ws_size;

  char* base = (char*)d_ws;
  size_t o = 0;
  auto alloc = [&](size_t bytes) -> void* {
    void* ptr = base + o;
    o = (o + bytes + 255) & ~(size_t)255;
    return ptr;
  };
  int* cnt = (int*)alloc((size_t)2 * N * 4);  // cnt + cur contiguous
  int* cur = cnt + N;
  int* off = (int*)alloc((size_t)(N + 1) * 4);
  int* bsum = (int*)alloc(1024);
  int* csr = (int*)alloc((size_t)E * 4);
  float* invd = (float*)alloc((size_t)N * 4);
  _Float16* w1 = (_Float16*)alloc((size_t)128 * 768 * 2);
  _Float16* w2 = (_Float16*)alloc((size_t)64 * 64 * 2);
  _Float16* w3 = (_Float16*)alloc((size_t)32 * 32 * 2);
  _Float16* w4 = (_Float16*)alloc((size_t)16 * 32 * 2);
  _Float16* P1 = (_Float16*)alloc((size_t)N * 64 * 2);
  _Float16* Q1 = (_Float16*)alloc((size_t)N * 64 * 2);
  _Float16* P2 = (_Float16*)alloc((size_t)N * 32 * 2);
  _Float16* Q2 = (_Float16*)alloc((size_t)N * 32 * 2);
  _Float16* P3 = (_Float16*)alloc((size_t)N * 16 * 2);
  _Float16* Q3 = (_Float16*)alloc((size_t)N * 16 * 2);
  _Float16* P4 = (_Float16*)alloc((size_t)N * 8 * 2);
  _Float16* Q4 = (_Float16*)alloc((size_t)N * 8 * 2);

  const int n4 = (2 * N + 3) / 4;
  const int prep_tot = 98304 + 4096 + 1024 + 512 + n4;
  prep_zero_kernel<<<(prep_tot + 255) / 256, 256, 0, stream>>>(
      W1l, W1r, W2l, W2r, W3l, W3r, W4l, W4r, w1, w2, w3, w4, (int4*)cnt, n4);

  deg_kernel<<<(E + 255) / 256, 256, 0, stream>>>(edst, cnt, E);
  const int nb = (N + 1 + 1023) / 1024;
  scan1_kernel<<<nb, 256, 0, stream>>>(cnt, off, bsum, invd, N);
  scan2_kernel<<<1, 128, 0, stream>>>(bsum, nb);
  scan3_kernel<<<(N + 1 + 255) / 256, 256, 0, stream>>>(off, bsum, N + 1);

  // MEGA: gemm1 (blocks [0, gemm_gb)) + sortfill (blocks [gemm_gb, ...))
  const int gemm_gb = (N + 127) / 128;
  const int sf_gb = (E + 255) / 256;
  gemm1_sortfill_kernel<<<gemm_gb + sf_gb, 256, 0, stream>>>(
      x, w1, b1, P1, Q1, N, gemm_gb, esrc, edst, off, cur, csr, E);

  // Layers 2-4 fused with preceding aggregation (edge-parallel gathers)
  const int gb = (N + 127) / 128;
  fused_agg_gemm_kernel<64, 64, 8, 64, 64, 32, 32>
      <<<gb, 512, 0, stream>>>(P1, Q1, off, csr, invd, w2, b2, P2, Q2, N);
  fused_agg_gemm_kernel<32, 32, 4, 32, 32, 16, 16>
      <<<gb, 512, 0, stream>>>(P2, Q2, off, csr, invd, w3, b3, P3, Q3, N);
  fused_agg_gemm_kernel<16, 32, 2, 16, 10, 5, 8>
      <<<gb, 512, 0, stream>>>(P3, Q3, off, csr, invd, w4, b4, P4, Q4, N);
  aggregate_last_kernel<<<(N + 31) / 32, 256, 0, stream>>>(P4, Q4, off, csr, invd, out, N);
}

// Round 14
// 252.280 us; speedup vs baseline: 1.4261x; 1.4261x over previous
//
#include <hip/hip_runtime.h>

using half8 = __attribute__((ext_vector_type(8))) _Float16;
using f32x4 = __attribute__((ext_vector_type(4))) float;

typedef __attribute__((address_space(3))) unsigned int lds_uint;
typedef __attribute__((address_space(1))) const unsigned int glb_uint;
__device__ __forceinline__ void async_copy16(const void* g, void* l) {
  __builtin_amdgcn_global_load_lds((glb_uint*)g, (lds_uint*)l, 16, 0, 0);
}

// raw barrier WITHOUT the implicit vmcnt(0) drain of __syncthreads()
__device__ __forceinline__ void raw_barrier() {
  asm volatile("" ::: "memory");
  __builtin_amdgcn_s_barrier();
  asm volatile("" ::: "memory");
}

// ---------------- prep weights (fp16) + zero cnt/cur, one dispatch ----------------
__global__ void prep_zero_kernel(const float* __restrict__ W1l, const float* __restrict__ W1r,
                                 const float* __restrict__ W2l, const float* __restrict__ W2r,
                                 const float* __restrict__ W3l, const float* __restrict__ W3r,
                                 const float* __restrict__ W4l, const float* __restrict__ W4r,
                                 _Float16* __restrict__ w1, _Float16* __restrict__ w2,
                                 _Float16* __restrict__ w3, _Float16* __restrict__ w4,
                                 int4* __restrict__ zp, int n4) {
  int i = blockIdx.x * 256 + threadIdx.x;
  if (i < 98304) {  // w1: 128*768
    int c = i / 768, k = i - c * 768;
    float v = (c < 64) ? W1l[k * 64 + c] : W1r[k * 64 + (c - 64)];
    w1[i] = (_Float16)v;
  } else if (i < 98304 + 4096) {  // w2: [64][64]
    int j = i - 98304;
    int c = j >> 6, k = j & 63;
    float v = (c < 32) ? W2l[k * 32 + c] : W2r[k * 32 + (c - 32)];
    w2[j] = (_Float16)v;
  } else if (i < 98304 + 4096 + 1024) {  // w3: [32][32]
    int j = i - (98304 + 4096);
    int c = j >> 5, k = j & 31;
    float v = (c < 16) ? W3l[k * 16 + c] : W3r[k * 16 + (c - 16)];
    w3[j] = (_Float16)v;
  } else if (i < 98304 + 4096 + 1024 + 512) {  // w4: [16][32]
    int j = i - (98304 + 4096 + 1024);
    int c = j >> 5, k = j & 31;
    float v = 0.f;
    if (k < 16) {
      if (c < 5) v = W4l[k * 5 + c];
      else if (c < 10) v = W4r[k * 5 + (c - 5)];
    }
    w4[j] = (_Float16)v;
  } else {
    int j = i - (98304 + 4096 + 1024 + 512);
    if (j < n4) zp[j] = make_int4(0, 0, 0, 0);
  }
}

// ---------------- CSR build ----------------
__global__ void deg_kernel(const int* __restrict__ dst, int* __restrict__ cnt, int e) {
  int i = blockIdx.x * 256 + threadIdx.x;
  if (i < e) atomicAdd(&cnt[dst[i]], 1);
}

__global__ void scan1_kernel(const int* __restrict__ cnt, int* __restrict__ off,
                             int* __restrict__ bsum, float* __restrict__ invd, int nodes) {
  __shared__ int sh[256];
  int tid = threadIdx.x;
  int base = blockIdx.x * 1024 + tid * 4;
  int a0 = (base + 0 < nodes) ? cnt[base + 0] : 0;
  int a1 = (base + 1 < nodes) ? cnt[base + 1] : 0;
  int a2 = (base + 2 < nodes) ? cnt[base + 2] : 0;
  int a3 = (base + 3 < nodes) ? cnt[base + 3] : 0;
  if (base + 0 < nodes) invd[base + 0] = a0 > 0 ? 1.0f / (float)a0 : 0.f;
  if (base + 1 < nodes) invd[base + 1] = a1 > 0 ? 1.0f / (float)a1 : 0.f;
  if (base + 2 < nodes) invd[base + 2] = a2 > 0 ? 1.0f / (float)a2 : 0.f;
  if (base + 3 < nodes) invd[base + 3] = a3 > 0 ? 1.0f / (float)a3 : 0.f;
  int s3 = a0 + a1 + a2 + a3;
  sh[tid] = s3;
  __syncthreads();
  for (int d = 1; d < 256; d <<= 1) {
    int v = (tid >= d) ? sh[tid - d] : 0;
    __syncthreads();
    sh[tid] += v;
    __syncthreads();
  }
  int excl = sh[tid] - s3;
  if (base + 0 <= nodes) off[base + 0] = excl;
  if (base + 1 <= nodes) off[base + 1] = excl + a0;
  if (base + 2 <= nodes) off[base + 2] = excl + a0 + a1;
  if (base + 3 <= nodes) off[base + 3] = excl + a0 + a1 + a2;
  if (tid == 255) bsum[blockIdx.x] = sh[255];
}

__global__ void scan2_kernel(int* __restrict__ bsum, int nb) {
  __shared__ int sh[128];
  int tid = threadIdx.x;
  int v = (tid < nb) ? bsum[tid] : 0;
  sh[tid] = v;
  __syncthreads();
  for (int d = 1; d < 128; d <<= 1) {
    int u = (tid >= d) ? sh[tid - d] : 0;
    __syncthreads();
    sh[tid] += u;
    __syncthreads();
  }
  if (tid < nb) bsum[tid] = sh[tid] - v;
}

__global__ void scan3_kernel(int* __restrict__ off, const int* __restrict__ bsum, int ntot) {
  int i = blockIdx.x * 256 + threadIdx.x;
  if (i < ntot) off[i] += bsum[i >> 10];
}

__global__ void sortfill_kernel(const int* __restrict__ src, const int* __restrict__ dst,
                                const int* __restrict__ off, int* __restrict__ cur,
                                int* __restrict__ csr, int e) {
  int i = blockIdx.x * 256 + threadIdx.x;
  if (i < e) {
    int d = dst[i];
    int pos = atomicAdd(&cur[d], 1);
    csr[off[d] + pos] = src[i];
  }
}

// ---------------- layer-1 MFMA GEMM (R8 config: best measured, ~120us plateau) --------
__global__ __launch_bounds__(256, 3) void gemm1_kernel(
    const float* __restrict__ x,       // [n][768]
    const _Float16* __restrict__ w16,  // [128][768]
    const float* __restrict__ bias,    // [64]
    _Float16* __restrict__ p, _Float16* __restrict__ q, int n) {
  constexpr int DI = 768, BK = 32, NT = DI / BK;
  __shared__ float aS[2][128 * BK];     // 2 x 16 KB
  __shared__ _Float16 bS[2][128 * BK];  // 2 x 8 KB
  int t = threadIdx.x;
  int lane = t & 63, w = t >> 6;
  int lm = lane & 15, lk = lane >> 4;
  int m0 = blockIdx.x * 128;

  const float* agp[4];
  int abase[4];
#pragma unroll
  for (int j = 0; j < 4; ++j) {
    int g = (j * 4 + w) * 64 + lane;
    int row = g >> 3, gi = g & 7;
    int gj = gi ^ (row & 7);
    int grow = m0 + row;
    if (grow >= n) grow = n - 1;
    agp[j] = x + (size_t)grow * DI + gj * 4;
    abase[j] = (j * 4 + w) * 256;
  }
  const _Float16* bgp[2];
  int bbase[2];
#pragma unroll
  for (int j = 0; j < 2; ++j) {
    int g = (j * 4 + w) * 64 + lane;
    int c = g >> 2, gi = g & 3;
    int gj = gi ^ ((c >> 1) & 3);
    bgp[j] = w16 + (size_t)c * DI + gj * 8;
    bbase[j] = (j * 4 + w) * 512;
  }

  f32x4 acc[2][8];
#pragma unroll
  for (int mi = 0; mi < 2; ++mi)
#pragma unroll
    for (int ni = 0; ni < 8; ++ni) acc[mi][ni] = (f32x4){0.f, 0.f, 0.f, 0.f};

  int r0l = w * 32 + lm, r1l = r0l + 16;
  int sw = lm & 7;
  int bsw = (lk ^ ((lm >> 1) & 3)) << 3;

  auto compute_tile = [&](const float* ab, const _Float16* bb) {
    f32x4 v0a = *(const f32x4*)(ab + r0l * 32 + (((lk * 2 + 0) ^ sw) << 2));
    f32x4 v0b = *(const f32x4*)(ab + r0l * 32 + (((lk * 2 + 1) ^ sw) << 2));
    f32x4 v1a = *(const f32x4*)(ab + r1l * 32 + (((lk * 2 + 0) ^ sw) << 2));
    f32x4 v1b = *(const f32x4*)(ab + r1l * 32 + (((lk * 2 + 1) ^ sw) << 2));
    half8 a0, a1;
#pragma unroll
    for (int j = 0; j < 4; ++j) {
      a0[j] = (_Float16)v0a[j]; a0[4 + j] = (_Float16)v0b[j];
      a1[j] = (_Float16)v1a[j]; a1[4 + j] = (_Float16)v1b[j];
    }
#pragma unroll
    for (int ni = 0; ni < 8; ++ni) {
      half8 b = *(const half8*)(bb + ni * 512 + lm * 32 + bsw);
      acc[0][ni] = __builtin_amdgcn_mfma_f32_16x16x32_f16(a0, b, acc[0][ni], 0, 0, 0);
      acc[1][ni] = __builtin_amdgcn_mfma_f32_16x16x32_f16(a1, b, acc[1][ni], 0, 0, 0);
    }
  };

#pragma unroll
  for (int j = 0; j < 4; ++j) async_copy16(agp[j], &aS[0][abase[j]]);
#pragma unroll
  for (int j = 0; j < 2; ++j) async_copy16(bgp[j], &bS[0][bbase[j]]);

  for (int ts = 0; ts < NT - 1; ++ts) {
    int cur = ts & 1;
    int kc = (ts + 1) * BK;
#pragma unroll
    for (int j = 0; j < 4; ++j) async_copy16(agp[j] + kc, &aS[cur ^ 1][abase[j]]);
#pragma unroll
    for (int j = 0; j < 2; ++j) async_copy16(bgp[j] + kc, &bS[cur ^ 1][bbase[j]]);
    asm volatile("s_waitcnt vmcnt(6)" ::: "memory");
    raw_barrier();
    compute_tile(aS[cur], bS[cur]);
    raw_barrier();
  }
  asm volatile("s_waitcnt vmcnt(0)" ::: "memory");
  raw_barrier();
  compute_tile(aS[(NT - 1) & 1], bS[(NT - 1) & 1]);

#pragma unroll
  for (int mi = 0; mi < 2; ++mi)
#pragma unroll
    for (int ni = 0; ni < 8; ++ni) {
      int col = ni * 16 + lm;
#pragma unroll
      for (int j = 0; j < 4; ++j) {
        int row = m0 + w * 32 + mi * 16 + lk * 4 + j;
        if (row < n) {
          float v = acc[mi][ni][j];
          if (col < 64) p[(size_t)row * 64 + col] = (_Float16)v;
          else q[(size_t)row * 64 + (col - 64)] = (_Float16)(v + bias[col - 64]);
        }
      }
    }
}

// ---------------- fused aggregate(+relu) -> gemm, 512 threads, WAVE-LOCAL sync --------
// Dataflow is wave-local: thread t aggregates node t>>2 => wave w owns nodes
// w*16..w*16+15; Phase B's A-fragment reads rows w*16+lm -- the SAME rows wave w wrote.
// So no block barrier is needed: s_waitcnt lgkmcnt(0) (per-wave DS ops complete in
// issue order) + sched_barrier(0) (rule #18: stop compiler hoisting dependent ds_reads
// past the inline-asm wait). Removes the block-wide max-deg straggler sync.
template <int DIR, int DIP, int PSI, int NC, int NCR, int DO, int PSO>
__global__ __launch_bounds__(512) void fused_agg_gemm_kernel(
    const _Float16* __restrict__ pin, const _Float16* __restrict__ qin,
    const int* __restrict__ off, const int* __restrict__ csr, const float* __restrict__ invd,
    const _Float16* __restrict__ w16, const float* __restrict__ bias,
    _Float16* __restrict__ pout, _Float16* __restrict__ qout, int n) {
  constexpr int SP = DIP + 8;
  constexpr int C8 = DIR / 8;
  constexpr int ACT = (C8 >= 4) ? 4 : C8;
  constexpr int CQ = C8 / ACT;
  constexpr int NF = NC / 16;
  __shared__ _Float16 hs[128 * SP];
  int t = threadIdx.x;
  int node_l = t >> 2, q4 = t & 3;
  int node = blockIdx.x * 128 + node_l;

  if (node < n) {
    if (q4 < ACT) {
      int e0 = off[node], e1 = off[node + 1];
      const half8* p8 = (const half8*)pin;
      float s[CQ][8];
#pragma unroll
      for (int c = 0; c < CQ; ++c)
#pragma unroll
        for (int j = 0; j < 8; ++j) s[c][j] = 0.f;
      int e = e0;
      for (; e + 2 <= e1; e += 2) {
        int i0 = csr[e], i1 = csr[e + 1];
        half8 v0[CQ], v1[CQ];
#pragma unroll
        for (int c = 0; c < CQ; ++c) v0[c] = p8[(size_t)i0 * PSI + q4 * CQ + c];
#pragma unroll
        for (int c = 0; c < CQ; ++c) v1[c] = p8[(size_t)i1 * PSI + q4 * CQ + c];
#pragma unroll
        for (int c = 0; c < CQ; ++c)
#pragma unroll
          for (int j = 0; j < 8; ++j) {
            s[c][j] += (float)v0[c][j];
            s[c][j] += (float)v1[c][j];
          }
      }
      if (e < e1) {
        int i0 = csr[e];
#pragma unroll
        for (int c = 0; c < CQ; ++c) {
          half8 v = p8[(size_t)i0 * PSI + q4 * CQ + c];
#pragma unroll
          for (int j = 0; j < 8; ++j) s[c][j] += (float)v[j];
        }
      }
      float id = invd[node];
#pragma unroll
      for (int c = 0; c < CQ; ++c) {
        half8 qv = ((const half8*)qin)[(size_t)node * PSI + q4 * CQ + c];
        half8 o;
#pragma unroll
        for (int j = 0; j < 8; ++j) o[j] = (_Float16)fmaxf(s[c][j] * id + (float)qv[j], 0.f);
        *(half8*)(hs + node_l * SP + (q4 * CQ + c) * 8) = o;
      }
    } else if (DIP > DIR && (q4 - ACT) < (DIP - DIR) / 8) {
      half8 z = {};
      *(half8*)(hs + node_l * SP + (C8 + (q4 - ACT)) * 8) = z;
    }
  }
  // wave-local fence instead of __syncthreads (dataflow is wave-local, see header)
  asm volatile("s_waitcnt lgkmcnt(0)" ::: "memory");
  __builtin_amdgcn_sched_barrier(0);

  int lane = t & 63, w = t >> 6;
  int lm = lane & 15, lk = lane >> 4;
  int row_l = w * 16 + lm;
  const _Float16* wp = w16 + (size_t)lm * DIP + lk * 8;
  f32x4 acc[NF];
#pragma unroll
  for (int ni = 0; ni < NF; ++ni) acc[ni] = (f32x4){0.f, 0.f, 0.f, 0.f};
#pragma unroll
  for (int kc = 0; kc < DIP; kc += 32) {
    half8 a = *(const half8*)(hs + row_l * SP + kc + lk * 8);
#pragma unroll
    for (int ni = 0; ni < NF; ++ni) {
      half8 b = *(const half8*)(wp + (size_t)ni * 16 * DIP + kc);
      acc[ni] = __builtin_amdgcn_mfma_f32_16x16x32_f16(a, b, acc[ni], 0, 0, 0);
    }
  }
#pragma unroll
  for (int ni = 0; ni < NF; ++ni) {
    int col = ni * 16 + lm;
    if (col >= NCR) continue;
#pragma unroll
    for (int j = 0; j < 4; ++j) {
      int row = blockIdx.x * 128 + w * 16 + lk * 4 + j;
      if (row < n) {
        float v = acc[ni][j];
        if (col < DO) pout[(size_t)row * PSO + col] = (_Float16)v;
        else qout[(size_t)row * PSO + (col - DO)] = (_Float16)(v + bias[col - DO]);
      }
    }
  }
}

// final aggregation: 1 thread/node, half8 gather per edge, unroll x2
__global__ __launch_bounds__(256) void aggregate_last_kernel(
    const _Float16* __restrict__ p, const _Float16* __restrict__ q,
    const int* __restrict__ off, const int* __restrict__ csr,
    const float* __restrict__ invd, float* __restrict__ out, int n) {
  int node = blockIdx.x * 256 + threadIdx.x;
  if (node >= n) return;
  int e0 = off[node], e1 = off[node + 1];
  const half8* p8 = (const half8*)p;
  float s[8];
#pragma unroll
  for (int j = 0; j < 8; ++j) s[j] = 0.f;
  int e = e0;
  for (; e + 2 <= e1; e += 2) {
    half8 v0 = p8[csr[e]];
    half8 v1 = p8[csr[e + 1]];
#pragma unroll
    for (int j = 0; j < 8; ++j) {
      s[j] += (float)v0[j];
      s[j] += (float)v1[j];
    }
  }
  if (e < e1) {
    half8 v = p8[csr[e]];
#pragma unroll
    for (int j = 0; j < 8; ++j) s[j] += (float)v[j];
  }
  float id = invd[node];
  half8 qv = ((const half8*)q)[node];
#pragma unroll
  for (int j = 0; j < 5; ++j) out[(size_t)node * 5 + j] = s[j] * id + (float)qv[j];
}

// ---------------- launch ----------------
extern "C" void kernel_launch(void* const* d_in, const int* in_sizes, int n_in,
                              void* d_out, int out_size, void* d_ws, size_t ws_size,
                              hipStream_t stream) {
  const float* x = (const float*)d_in[0];
  const int* ei = (const int*)d_in[1];
  const int E = in_sizes[1] / 2;
  const int* esrc = ei;
  const int* edst = ei + E;
  const float* W1l = (const float*)d_in[3];
  const float* W1r = (const float*)d_in[4];
  const float* b1 = (const float*)d_in[5];
  const float* W2l = (const float*)d_in[6];
  const float* W2r = (const float*)d_in[7];
  const float* b2 = (const float*)d_in[8];
  const float* W3l = (const float*)d_in[9];
  const float* W3r = (const float*)d_in[10];
  const float* b3 = (const float*)d_in[11];
  const float* W4l = (const float*)d_in[12];
  const float* W4r = (const float*)d_in[13];
  const float* b4 = (const float*)d_in[14];
  const int N = in_sizes[0] / 768;
  float* out = (float*)d_out;
  (void)n_in; (void)out_size; (void)ws_size;

  char* base = (char*)d_ws;
  size_t o = 0;
  auto alloc = [&](size_t bytes) -> void* {
    void* ptr = base + o;
    o = (o + bytes + 255) & ~(size_t)255;
    return ptr;
  };
  int* cnt = (int*)alloc((size_t)2 * N * 4);  // cnt + cur contiguous
  int* cur = cnt + N;
  int* off = (int*)alloc((size_t)(N + 1) * 4);
  int* bsum = (int*)alloc(1024);
  int* csr = (int*)alloc((size_t)E * 4);
  float* invd = (float*)alloc((size_t)N * 4);
  _Float16* w1 = (_Float16*)alloc((size_t)128 * 768 * 2);
  _Float16* w2 = (_Float16*)alloc((size_t)64 * 64 * 2);
  _Float16* w3 = (_Float16*)alloc((size_t)32 * 32 * 2);
  _Float16* w4 = (_Float16*)alloc((size_t)16 * 32 * 2);
  _Float16* P1 = (_Float16*)alloc((size_t)N * 64 * 2);
  _Float16* Q1 = (_Float16*)alloc((size_t)N * 64 * 2);
  _Float16* P2 = (_Float16*)alloc((size_t)N * 32 * 2);
  _Float16* Q2 = (_Float16*)alloc((size_t)N * 32 * 2);
  _Float16* P3 = (_Float16*)alloc((size_t)N * 16 * 2);
  _Float16* Q3 = (_Float16*)alloc((size_t)N * 16 * 2);
  _Float16* P4 = (_Float16*)alloc((size_t)N * 8 * 2);
  _Float16* Q4 = (_Float16*)alloc((size_t)N * 8 * 2);

  const int n4 = (2 * N + 3) / 4;
  const int prep_tot = 98304 + 4096 + 1024 + 512 + n4;
  prep_zero_kernel<<<(prep_tot + 255) / 256, 256, 0, stream>>>(
      W1l, W1r, W2l, W2r, W3l, W3r, W4l, W4r, w1, w2, w3, w4, (int4*)cnt, n4);

  deg_kernel<<<(E + 255) / 256, 256, 0, stream>>>(edst, cnt, E);
  const int nb = (N + 1 + 1023) / 1024;
  scan1_kernel<<<nb, 256, 0, stream>>>(cnt, off, bsum, invd, N);
  scan2_kernel<<<1, 128, 0, stream>>>(bsum, nb);
  scan3_kernel<<<(N + 1 + 255) / 256, 256, 0, stream>>>(off, bsum, N + 1);
  sortfill_kernel<<<(E + 255) / 256, 256, 0, stream>>>(esrc, edst, off, cur, csr, E);

  // Layer 1: 768 -> 64 (R8-config LDS-staged MFMA)
  gemm1_kernel<<<(N + 127) / 128, 256, 0, stream>>>(x, w1, b1, P1, Q1, N);
  // Layers 2-4 fused with preceding aggregation (512-thread blocks, wave-local sync)
  const int gb = (N + 127) / 128;
  fused_agg_gemm_kernel<64, 64, 8, 64, 64, 32, 32>
      <<<gb, 512, 0, stream>>>(P1, Q1, off, csr, invd, w2, b2, P2, Q2, N);
  fused_agg_gemm_kernel<32, 32, 4, 32, 32, 16, 16>
      <<<gb, 512, 0, stream>>>(P2, Q2, off, csr, invd, w3, b3, P3, Q3, N);
  fused_agg_gemm_kernel<16, 32, 2, 16, 10, 5, 8>
      <<<gb, 512, 0, stream>>>(P3, Q3, off, csr, invd, w4, b4, P4, Q4, N);
  aggregate_last_kernel<<<(N + 255) / 256, 256, 0, stream>>>(P4, Q4, off, csr, invd, out, N);
}

// Round 15
// 239.194 us; speedup vs baseline: 1.5041x; 1.0547x over previous
//
#include <hip/hip_runtime.h>

using half8 = __attribute__((ext_vector_type(8))) _Float16;
using f32x4 = __attribute__((ext_vector_type(4))) float;

typedef __attribute__((address_space(3))) unsigned int lds_uint;
typedef __attribute__((address_space(1))) const unsigned int glb_uint;
__device__ __forceinline__ void async_copy16(const void* g, void* l) {
  __builtin_amdgcn_global_load_lds((glb_uint*)g, (lds_uint*)l, 16, 0, 0);
}

// raw barrier WITHOUT the implicit vmcnt(0) drain of __syncthreads()
__device__ __forceinline__ void raw_barrier() {
  asm volatile("" ::: "memory");
  __builtin_amdgcn_s_barrier();
  asm volatile("" ::: "memory");
}

// ---------------- prep weights (fp16) + zero cnt/cur, one dispatch ----------------
__global__ void prep_zero_kernel(const float* __restrict__ W1l, const float* __restrict__ W1r,
                                 const float* __restrict__ W2l, const float* __restrict__ W2r,
                                 const float* __restrict__ W3l, const float* __restrict__ W3r,
                                 const float* __restrict__ W4l, const float* __restrict__ W4r,
                                 _Float16* __restrict__ w1, _Float16* __restrict__ w2,
                                 _Float16* __restrict__ w3, _Float16* __restrict__ w4,
                                 int4* __restrict__ zp, int n4) {
  int i = blockIdx.x * 256 + threadIdx.x;
  if (i < 98304) {  // w1: 128*768
    int c = i / 768, k = i - c * 768;
    float v = (c < 64) ? W1l[k * 64 + c] : W1r[k * 64 + (c - 64)];
    w1[i] = (_Float16)v;
  } else if (i < 98304 + 4096) {  // w2: [64][64]
    int j = i - 98304;
    int c = j >> 6, k = j & 63;
    float v = (c < 32) ? W2l[k * 32 + c] : W2r[k * 32 + (c - 32)];
    w2[j] = (_Float16)v;
  } else if (i < 98304 + 4096 + 1024) {  // w3: [32][32]
    int j = i - (98304 + 4096);
    int c = j >> 5, k = j & 31;
    float v = (c < 16) ? W3l[k * 16 + c] : W3r[k * 16 + (c - 16)];
    w3[j] = (_Float16)v;
  } else if (i < 98304 + 4096 + 1024 + 512) {  // w4: [16][32]
    int j = i - (98304 + 4096 + 1024);
    int c = j >> 5, k = j & 31;
    float v = 0.f;
    if (k < 16) {
      if (c < 5) v = W4l[k * 5 + c];
      else if (c < 10) v = W4r[k * 5 + (c - 5)];
    }
    w4[j] = (_Float16)v;
  } else {
    int j = i - (98304 + 4096 + 1024 + 512);
    if (j < n4) zp[j] = make_int4(0, 0, 0, 0);
  }
}

// ---------------- CSR build ----------------
__global__ void deg_kernel(const int* __restrict__ dst, int* __restrict__ cnt, int e) {
  int i = blockIdx.x * 256 + threadIdx.x;
  if (i < e) atomicAdd(&cnt[dst[i]], 1);
}

__global__ void scan1_kernel(const int* __restrict__ cnt, int* __restrict__ off,
                             int* __restrict__ bsum, float* __restrict__ invd, int nodes) {
  __shared__ int sh[256];
  int tid = threadIdx.x;
  int base = blockIdx.x * 1024 + tid * 4;
  int a0 = (base + 0 < nodes) ? cnt[base + 0] : 0;
  int a1 = (base + 1 < nodes) ? cnt[base + 1] : 0;
  int a2 = (base + 2 < nodes) ? cnt[base + 2] : 0;
  int a3 = (base + 3 < nodes) ? cnt[base + 3] : 0;
  if (base + 0 < nodes) invd[base + 0] = a0 > 0 ? 1.0f / (float)a0 : 0.f;
  if (base + 1 < nodes) invd[base + 1] = a1 > 0 ? 1.0f / (float)a1 : 0.f;
  if (base + 2 < nodes) invd[base + 2] = a2 > 0 ? 1.0f / (float)a2 : 0.f;
  if (base + 3 < nodes) invd[base + 3] = a3 > 0 ? 1.0f / (float)a3 : 0.f;
  int s3 = a0 + a1 + a2 + a3;
  sh[tid] = s3;
  __syncthreads();
  for (int d = 1; d < 256; d <<= 1) {
    int v = (tid >= d) ? sh[tid - d] : 0;
    __syncthreads();
    sh[tid] += v;
    __syncthreads();
  }
  int excl = sh[tid] - s3;
  if (base + 0 <= nodes) off[base + 0] = excl;
  if (base + 1 <= nodes) off[base + 1] = excl + a0;
  if (base + 2 <= nodes) off[base + 2] = excl + a0 + a1;
  if (base + 3 <= nodes) off[base + 3] = excl + a0 + a1 + a2;
  if (tid == 255) bsum[blockIdx.x] = sh[255];
}

__global__ void scan2_kernel(int* __restrict__ bsum, int nb) {
  __shared__ int sh[128];
  int tid = threadIdx.x;
  int v = (tid < nb) ? bsum[tid] : 0;
  sh[tid] = v;
  __syncthreads();
  for (int d = 1; d < 128; d <<= 1) {
    int u = (tid >= d) ? sh[tid - d] : 0;
    __syncthreads();
    sh[tid] += u;
    __syncthreads();
  }
  if (tid < nb) bsum[tid] = sh[tid] - v;
}

__global__ void scan3_kernel(int* __restrict__ off, const int* __restrict__ bsum, int ntot) {
  int i = blockIdx.x * 256 + threadIdx.x;
  if (i < ntot) off[i] += bsum[i >> 10];
}

// ---------------- MEGA: layer-1 GEMM blocks + sortfill blocks, one dispatch ----------
// Isolated retry of R13's grid-fusion (R13 bundled it with a bad Phase-A rewrite that
// caused the regression). sortfill (~10-15us of random atomics) backfills CUs during
// the gemm's last scheduling round; its dispatch slot disappears. gemm path is the
// R8/R11/R14 config verbatim (~105us plateau).
__global__ __launch_bounds__(256, 3) void gemm1_sortfill_kernel(
    const float* __restrict__ x, const _Float16* __restrict__ w16,
    const float* __restrict__ bias, _Float16* __restrict__ p, _Float16* __restrict__ q,
    int n, int gemm_gb, const int* __restrict__ esrc, const int* __restrict__ edst,
    const int* __restrict__ off, int* __restrict__ cur, int* __restrict__ csr, int E) {
  if ((int)blockIdx.x >= gemm_gb) {
    // ---- sortfill path ----
    int i = ((int)blockIdx.x - gemm_gb) * 256 + threadIdx.x;
    if (i < E) {
      int d = edst[i];
      int pos = atomicAdd(&cur[d], 1);
      csr[off[d] + pos] = esrc[i];
    }
    return;
  }
  // ---- gemm path (R8 config) ----
  constexpr int DI = 768, BK = 32, NT = DI / BK;
  __shared__ float aS[2][128 * BK];     // 2 x 16 KB
  __shared__ _Float16 bS[2][128 * BK];  // 2 x 8 KB
  int t = threadIdx.x;
  int lane = t & 63, w = t >> 6;
  int lm = lane & 15, lk = lane >> 4;
  int m0 = blockIdx.x * 128;

  const float* agp[4];
  int abase[4];
#pragma unroll
  for (int j = 0; j < 4; ++j) {
    int g = (j * 4 + w) * 64 + lane;
    int row = g >> 3, gi = g & 7;
    int gj = gi ^ (row & 7);
    int grow = m0 + row;
    if (grow >= n) grow = n - 1;
    agp[j] = x + (size_t)grow * DI + gj * 4;
    abase[j] = (j * 4 + w) * 256;
  }
  const _Float16* bgp[2];
  int bbase[2];
#pragma unroll
  for (int j = 0; j < 2; ++j) {
    int g = (j * 4 + w) * 64 + lane;
    int c = g >> 2, gi = g & 3;
    int gj = gi ^ ((c >> 1) & 3);
    bgp[j] = w16 + (size_t)c * DI + gj * 8;
    bbase[j] = (j * 4 + w) * 512;
  }

  f32x4 acc[2][8];
#pragma unroll
  for (int mi = 0; mi < 2; ++mi)
#pragma unroll
    for (int ni = 0; ni < 8; ++ni) acc[mi][ni] = (f32x4){0.f, 0.f, 0.f, 0.f};

  int r0l = w * 32 + lm, r1l = r0l + 16;
  int sw = lm & 7;
  int bsw = (lk ^ ((lm >> 1) & 3)) << 3;

  auto compute_tile = [&](const float* ab, const _Float16* bb) {
    f32x4 v0a = *(const f32x4*)(ab + r0l * 32 + (((lk * 2 + 0) ^ sw) << 2));
    f32x4 v0b = *(const f32x4*)(ab + r0l * 32 + (((lk * 2 + 1) ^ sw) << 2));
    f32x4 v1a = *(const f32x4*)(ab + r1l * 32 + (((lk * 2 + 0) ^ sw) << 2));
    f32x4 v1b = *(const f32x4*)(ab + r1l * 32 + (((lk * 2 + 1) ^ sw) << 2));
    half8 a0, a1;
#pragma unroll
    for (int j = 0; j < 4; ++j) {
      a0[j] = (_Float16)v0a[j]; a0[4 + j] = (_Float16)v0b[j];
      a1[j] = (_Float16)v1a[j]; a1[4 + j] = (_Float16)v1b[j];
    }
#pragma unroll
    for (int ni = 0; ni < 8; ++ni) {
      half8 b = *(const half8*)(bb + ni * 512 + lm * 32 + bsw);
      acc[0][ni] = __builtin_amdgcn_mfma_f32_16x16x32_f16(a0, b, acc[0][ni], 0, 0, 0);
      acc[1][ni] = __builtin_amdgcn_mfma_f32_16x16x32_f16(a1, b, acc[1][ni], 0, 0, 0);
    }
  };

#pragma unroll
  for (int j = 0; j < 4; ++j) async_copy16(agp[j], &aS[0][abase[j]]);
#pragma unroll
  for (int j = 0; j < 2; ++j) async_copy16(bgp[j], &bS[0][bbase[j]]);

  for (int ts = 0; ts < NT - 1; ++ts) {
    int cur2 = ts & 1;
    int kc = (ts + 1) * BK;
#pragma unroll
    for (int j = 0; j < 4; ++j) async_copy16(agp[j] + kc, &aS[cur2 ^ 1][abase[j]]);
#pragma unroll
    for (int j = 0; j < 2; ++j) async_copy16(bgp[j] + kc, &bS[cur2 ^ 1][bbase[j]]);
    asm volatile("s_waitcnt vmcnt(6)" ::: "memory");
    raw_barrier();
    compute_tile(aS[cur2], bS[cur2]);
    raw_barrier();
  }
  asm volatile("s_waitcnt vmcnt(0)" ::: "memory");
  raw_barrier();
  compute_tile(aS[(NT - 1) & 1], bS[(NT - 1) & 1]);

#pragma unroll
  for (int mi = 0; mi < 2; ++mi)
#pragma unroll
    for (int ni = 0; ni < 8; ++ni) {
      int col = ni * 16 + lm;
#pragma unroll
      for (int j = 0; j < 4; ++j) {
        int row = m0 + w * 32 + mi * 16 + lk * 4 + j;
        if (row < n) {
          float v = acc[mi][ni][j];
          if (col < 64) p[(size_t)row * 64 + col] = (_Float16)v;
          else q[(size_t)row * 64 + (col - 64)] = (_Float16)(v + bias[col - 64]);
        }
      }
    }
}

// ---------------- fused aggregate(+relu) -> gemm, 512 threads, WAVE-LOCAL sync --------
// (R14 version, unchanged.) Dataflow is wave-local: thread t aggregates node t>>2 =>
// wave w owns nodes w*16..w*16+15; Phase B reads rows w*16+lm -- same rows wave w wrote.
template <int DIR, int DIP, int PSI, int NC, int NCR, int DO, int PSO>
__global__ __launch_bounds__(512) void fused_agg_gemm_kernel(
    const _Float16* __restrict__ pin, const _Float16* __restrict__ qin,
    const int* __restrict__ off, const int* __restrict__ csr, const float* __restrict__ invd,
    const _Float16* __restrict__ w16, const float* __restrict__ bias,
    _Float16* __restrict__ pout, _Float16* __restrict__ qout, int n) {
  constexpr int SP = DIP + 8;
  constexpr int C8 = DIR / 8;
  constexpr int ACT = (C8 >= 4) ? 4 : C8;
  constexpr int CQ = C8 / ACT;
  constexpr int NF = NC / 16;
  __shared__ _Float16 hs[128 * SP];
  int t = threadIdx.x;
  int node_l = t >> 2, q4 = t & 3;
  int node = blockIdx.x * 128 + node_l;

  if (node < n) {
    if (q4 < ACT) {
      int e0 = off[node], e1 = off[node + 1];
      const half8* p8 = (const half8*)pin;
      float s[CQ][8];
#pragma unroll
      for (int c = 0; c < CQ; ++c)
#pragma unroll
        for (int j = 0; j < 8; ++j) s[c][j] = 0.f;
      int e = e0;
      for (; e + 2 <= e1; e += 2) {
        int i0 = csr[e], i1 = csr[e + 1];
        half8 v0[CQ], v1[CQ];
#pragma unroll
        for (int c = 0; c < CQ; ++c) v0[c] = p8[(size_t)i0 * PSI + q4 * CQ + c];
#pragma unroll
        for (int c = 0; c < CQ; ++c) v1[c] = p8[(size_t)i1 * PSI + q4 * CQ + c];
#pragma unroll
        for (int c = 0; c < CQ; ++c)
#pragma unroll
          for (int j = 0; j < 8; ++j) {
            s[c][j] += (float)v0[c][j];
            s[c][j] += (float)v1[c][j];
          }
      }
      if (e < e1) {
        int i0 = csr[e];
#pragma unroll
        for (int c = 0; c < CQ; ++c) {
          half8 v = p8[(size_t)i0 * PSI + q4 * CQ + c];
#pragma unroll
          for (int j = 0; j < 8; ++j) s[c][j] += (float)v[j];
        }
      }
      float id = invd[node];
#pragma unroll
      for (int c = 0; c < CQ; ++c) {
        half8 qv = ((const half8*)qin)[(size_t)node * PSI + q4 * CQ + c];
        half8 o;
#pragma unroll
        for (int j = 0; j < 8; ++j) o[j] = (_Float16)fmaxf(s[c][j] * id + (float)qv[j], 0.f);
        *(half8*)(hs + node_l * SP + (q4 * CQ + c) * 8) = o;
      }
    } else if (DIP > DIR && (q4 - ACT) < (DIP - DIR) / 8) {
      half8 z = {};
      *(half8*)(hs + node_l * SP + (C8 + (q4 - ACT)) * 8) = z;
    }
  }
  // wave-local fence instead of __syncthreads (dataflow is wave-local, see header)
  asm volatile("s_waitcnt lgkmcnt(0)" ::: "memory");
  __builtin_amdgcn_sched_barrier(0);

  int lane = t & 63, w = t >> 6;
  int lm = lane & 15, lk = lane >> 4;
  int row_l = w * 16 + lm;
  const _Float16* wp = w16 + (size_t)lm * DIP + lk * 8;
  f32x4 acc[NF];
#pragma unroll
  for (int ni = 0; ni < NF; ++ni) acc[ni] = (f32x4){0.f, 0.f, 0.f, 0.f};
#pragma unroll
  for (int kc = 0; kc < DIP; kc += 32) {
    half8 a = *(const half8*)(hs + row_l * SP + kc + lk * 8);
#pragma unroll
    for (int ni = 0; ni < NF; ++ni) {
      half8 b = *(const half8*)(wp + (size_t)ni * 16 * DIP + kc);
      acc[ni] = __builtin_amdgcn_mfma_f32_16x16x32_f16(a, b, acc[ni], 0, 0, 0);
    }
  }
#pragma unroll
  for (int ni = 0; ni < NF; ++ni) {
    int col = ni * 16 + lm;
    if (col >= NCR) continue;
#pragma unroll
    for (int j = 0; j < 4; ++j) {
      int row = blockIdx.x * 128 + w * 16 + lk * 4 + j;
      if (row < n) {
        float v = acc[ni][j];
        if (col < DO) pout[(size_t)row * PSO + col] = (_Float16)v;
        else qout[(size_t)row * PSO + (col - DO)] = (_Float16)(v + bias[col - DO]);
      }
    }
  }
}

// final aggregation: 1 thread/node, half8 gather per edge, unroll x2
__global__ __launch_bounds__(256) void aggregate_last_kernel(
    const _Float16* __restrict__ p, const _Float16* __restrict__ q,
    const int* __restrict__ off, const int* __restrict__ csr,
    const float* __restrict__ invd, float* __restrict__ out, int n) {
  int node = blockIdx.x * 256 + threadIdx.x;
  if (node >= n) return;
  int e0 = off[node], e1 = off[node + 1];
  const half8* p8 = (const half8*)p;
  float s[8];
#pragma unroll
  for (int j = 0; j < 8; ++j) s[j] = 0.f;
  int e = e0;
  for (; e + 2 <= e1; e += 2) {
    half8 v0 = p8[csr[e]];
    half8 v1 = p8[csr[e + 1]];
#pragma unroll
    for (int j = 0; j < 8; ++j) {
      s[j] += (float)v0[j];
      s[j] += (float)v1[j];
    }
  }
  if (e < e1) {
    half8 v = p8[csr[e]];
#pragma unroll
    for (int j = 0; j < 8; ++j) s[j] += (float)v[j];
  }
  float id = invd[node];
  half8 qv = ((const half8*)q)[node];
#pragma unroll
  for (int j = 0; j < 5; ++j) out[(size_t)node * 5 + j] = s[j] * id + (float)qv[j];
}

// ---------------- launch ----------------
extern "C" void kernel_launch(void* const* d_in, const int* in_sizes, int n_in,
                              void* d_out, int out_size, void* d_ws, size_t ws_size,
                              hipStream_t stream) {
  const float* x = (const float*)d_in[0];
  const int* ei = (const int*)d_in[1];
  const int E = in_sizes[1] / 2;
  const int* esrc = ei;
  const int* edst = ei + E;
  const float* W1l = (const float*)d_in[3];
  const float* W1r = (const float*)d_in[4];
  const float* b1 = (const float*)d_in[5];
  const float* W2l = (const float*)d_in[6];
  const float* W2r = (const float*)d_in[7];
  const float* b2 = (const float*)d_in[8];
  const float* W3l = (const float*)d_in[9];
  const float* W3r = (const float*)d_in[10];
  const float* b3 = (const float*)d_in[11];
  const float* W4l = (const float*)d_in[12];
  const float* W4r = (const float*)d_in[13];
  const float* b4 = (const float*)d_in[14];
  const int N = in_sizes[0] / 768;
  float* out = (float*)d_out;
  (void)n_in; (void)out_size; (void)ws_size;

  char* base = (char*)d_ws;
  size_t o = 0;
  auto alloc = [&](size_t bytes) -> void* {
    void* ptr = base + o;
    o = (o + bytes + 255) & ~(size_t)255;
    return ptr;
  };
  int* cnt = (int*)alloc((size_t)2 * N * 4);  // cnt + cur contiguous
  int* cur = cnt + N;
  int* off = (int*)alloc((size_t)(N + 1) * 4);
  int* bsum = (int*)alloc(1024);
  int* csr = (int*)alloc((size_t)E * 4);
  float* invd = (float*)alloc((size_t)N * 4);
  _Float16* w1 = (_Float16*)alloc((size_t)128 * 768 * 2);
  _Float16* w2 = (_Float16*)alloc((size_t)64 * 64 * 2);
  _Float16* w3 = (_Float16*)alloc((size_t)32 * 32 * 2);
  _Float16* w4 = (_Float16*)alloc((size_t)16 * 32 * 2);
  _Float16* P1 = (_Float16*)alloc((size_t)N * 64 * 2);
  _Float16* Q1 = (_Float16*)alloc((size_t)N * 64 * 2);
  _Float16* P2 = (_Float16*)alloc((size_t)N * 32 * 2);
  _Float16* Q2 = (_Float16*)alloc((size_t)N * 32 * 2);
  _Float16* P3 = (_Float16*)alloc((size_t)N * 16 * 2);
  _Float16* Q3 = (_Float16*)alloc((size_t)N * 16 * 2);
  _Float16* P4 = (_Float16*)alloc((size_t)N * 8 * 2);
  _Float16* Q4 = (_Float16*)alloc((size_t)N * 8 * 2);

  const int n4 = (2 * N + 3) / 4;
  const int prep_tot = 98304 + 4096 + 1024 + 512 + n4;
  prep_zero_kernel<<<(prep_tot + 255) / 256, 256, 0, stream>>>(
      W1l, W1r, W2l, W2r, W3l, W3r, W4l, W4r, w1, w2, w3, w4, (int4*)cnt, n4);

  deg_kernel<<<(E + 255) / 256, 256, 0, stream>>>(edst, cnt, E);
  const int nb = (N + 1 + 1023) / 1024;
  scan1_kernel<<<nb, 256, 0, stream>>>(cnt, off, bsum, invd, N);
  scan2_kernel<<<1, 128, 0, stream>>>(bsum, nb);
  scan3_kernel<<<(N + 1 + 255) / 256, 256, 0, stream>>>(off, bsum, N + 1);

  // MEGA: gemm1 (blocks [0, gemm_gb)) + sortfill (blocks [gemm_gb, ...))
  const int gemm_gb = (N + 127) / 128;
  const int sf_gb = (E + 255) / 256;
  gemm1_sortfill_kernel<<<gemm_gb + sf_gb, 256, 0, stream>>>(
      x, w1, b1, P1, Q1, N, gemm_gb, esrc, edst, off, cur, csr, E);

  // Layers 2-4 fused with preceding aggregation (512-thread blocks, wave-local sync)
  const int gb = (N + 127) / 128;
  fused_agg_gemm_kernel<64, 64, 8, 64, 64, 32, 32>
      <<<gb, 512, 0, stream>>>(P1, Q1, off, csr, invd, w2, b2, P2, Q2, N);
  fused_agg_gemm_kernel<32, 32, 4, 32, 32, 16, 16>
      <<<gb, 512, 0, stream>>>(P2, Q2, off, csr, invd, w3, b3, P3, Q3, N);
  fused_agg_gemm_kernel<16, 32, 2, 16, 10, 5, 8>
      <<<gb, 512, 0, stream>>>(P3, Q3, off, csr, invd, w4, b4, P4, Q4, N);
  aggregate_last_kernel<<<(N + 255) / 256, 256, 0, stream>>>(P4, Q4, off, csr, invd, out, N);
}